// Round 1
// baseline (860.458 us; speedup 1.0000x reference)
//
#include <hip/hip_runtime.h>
#include <math.h>
#include <stdint.h>

// R1: replace both gate GEMMs (m97-class 2-barrier structure, measured 813 TF,
// MfmaUtil 35%) with the verified 256x256 8-phase counted-vmcnt template
// (T1 XCD swizzle + T2 LDS XOR swizzle + T3/T4 8-phase counted vmcnt + T5 setprio).
// Split-bf16 i,c GEMM is re-expressed as one standard GEMM with K=3x1536=4608 via
// per-K-tile source selection: kt in [0,24): Ahi*Whi, [24,48): Alo*Whi, [48,72): Ahi*Wlo.

#define DI static __device__ __forceinline__

typedef __bf16 bf16x8 __attribute__((ext_vector_type(8)));
typedef float f32x4 __attribute__((ext_vector_type(4)));
typedef float float4v __attribute__((ext_vector_type(4)));
typedef unsigned short u16;
typedef unsigned short u16x4 __attribute__((ext_vector_type(4)));

DI float b2f(u16 s) {
    unsigned u = ((unsigned)s) << 16;
    float f;
    __builtin_memcpy(&f, &u, 4);
    return f;
}
DI u16 f2b(float f) {
    unsigned x;
    __builtin_memcpy(&x, &f, 4);
    unsigned r = x + 0x7FFFu + ((x >> 16) & 1u);
    return (u16)(r >> 16);
}

// async global->LDS, 16B/lane; LDS dest = wave-uniform base + lane*16 (linear!)
DI void gl_lds(const u16* g, u16* l) {
    __builtin_amdgcn_global_load_lds(
        (__attribute__((address_space(1))) void*)g,
        (__attribute__((address_space(3))) void*)l,
        16, 0, 0);
}

DI float fast_tanh(float x) {
    float xc = fminf(fmaxf(x, -15.f), 15.f);
    float e = __expf(2.0f * xc);
    return (e - 1.f) / (e + 1.f);
}

// ============ pack kernels (unchanged) ============
__global__ void pack_A(const float* __restrict__ inp, const float* __restrict__ hx,
                       u16* __restrict__ Ahi, u16* __restrict__ Alo) {
    const int r = blockIdx.x;
    const int k = threadIdx.x * 4;
    float4v v = (k < 1024) ? *(const float4v*)(inp + (size_t)r * 1024 + k)
                           : *(const float4v*)(hx + (size_t)r * 512 + (k - 1024));
    u16x4 h, l;
#pragma unroll
    for (int e = 0; e < 4; ++e) {
        h[e] = f2b(v[e]);
        l[e] = f2b(v[e] - b2f(h[e]));
    }
    *(u16x4*)(Ahi + (size_t)r * 1536 + k) = h;
    *(u16x4*)(Alo + (size_t)r * 1536 + k) = l;
}

// Whi all 8192 gate-rows; Wlo compacted: rows [0,2048)=i-lo, [2048,4096)=c-lo.
__global__ void pack_W(const float* __restrict__ wx, const float* __restrict__ wh,
                       u16* __restrict__ Whi, u16* __restrict__ Wlo) {
    const int g = blockIdx.x;
    const int k = threadIdx.x * 4;
    float4v v = (k < 1024) ? *(const float4v*)(wx + (size_t)g * 1024 + k)
                           : *(const float4v*)(wh + (size_t)g * 512 + (k - 1024));
    u16x4 h, l;
#pragma unroll
    for (int e = 0; e < 4; ++e) {
        h[e] = f2b(v[e]);
        l[e] = f2b(v[e] - b2f(h[e]));
    }
    *(u16x4*)(Whi + (size_t)g * 1536 + k) = h;
    int lr = -1;
    if (g < 2048) lr = g;
    else if (g >= 4096 && g < 6144) lr = g - 2048;
    if (lr >= 0) *(u16x4*)(Wlo + (size_t)lr * 1536 + k) = l;
}

__global__ void pack_flat_bf16(const float* __restrict__ src, u16* __restrict__ dst) {
    const size_t t = ((size_t)blockIdx.x * blockDim.x + threadIdx.x) * 4;
    float4v v = *(const float4v*)(src + t);
    u16x4 o;
#pragma unroll
    for (int e = 0; e < 4; ++e) o[e] = f2b(v[e]);
    *(u16x4*)(dst + t) = o;
}

// ============ 8-phase 256x256 GEMM core (shared macros) ============
// Geometry: BM=BN=256, BK=64, 512 thr = 8 waves (2M x 4N), per-wave 128x64 out.
// LDS 128 KiB: A[2buf][256][64]u16 @0, W[2buf][256][64]u16 @32768 (u16 idx).
// T2 swizzle: within each 128B row, 16B-chunk c stored at c ^ (row&7).
//   - stage: linear LDS dest (gl_lds requirement), inverse-swizzled global source
//   - read:  chunk (kk*4 + (lane>>4)) ^ (lane&7)  (row&7 == lane&7 for all frags)
// Schedule per iter (2 K-tiles t=2I,t+1; buf0=even,buf1=odd). Region-safety:
//   bufX A-halves fully read after P3(P7), W-halves after P2(P6) of their group.
//   P1: stage W-h1(t+1)->buf1   P2: A-h1(t+1)->buf1   P3: W-h0(t+2)->buf0
//   P4: W-h1(t+2)->buf0 ; vmcnt(4) [t+1 complete: 4 loads issued after its last]
//   P5: A-h0(t+2)->buf0   P6: A-h1(t+2)->buf0   P7: W-h0(t+3)->buf1
//   P8: A-h0(t+3)->buf1 ; vmcnt(4) [t+2 complete]
// Counted vmcnt never drains to 0 in steady state (T4). 2 gl_lds per phase per wave.

#define PH_FENCE() __builtin_amdgcn_sched_barrier(0)
#define PH_BAR()                           \
    do {                                   \
        PH_FENCE();                        \
        __builtin_amdgcn_s_barrier();      \
        PH_FENCE();                        \
    } while (0)
#define VMCNT(n) asm volatile("s_waitcnt vmcnt(" #n ")" ::: "memory")

#define LDA_(b, mh)                                                                   \
    do {                                                                              \
        _Pragma("unroll") for (int i_ = 0; i_ < 4; ++i_) {                            \
            Af[i_][0] = *(const bf16x8*)(pA + (b)*16384 + ((mh)*4 + i_) * 1024 + cs0);\
            Af[i_][1] = *(const bf16x8*)(pA + (b)*16384 + ((mh)*4 + i_) * 1024 + cs1);\
        }                                                                             \
    } while (0)

#define LDW_(b, jj)                                                                   \
    do {                                                                              \
        _Pragma("unroll") for (int j_ = 0; j_ < 2; ++j_) {                            \
            Wf[(jj)*2 + j_][0] =                                                      \
                *(const bf16x8*)(pW + (b)*16384 + ((jj)*2 + j_) * 1024 + cs0);        \
            Wf[(jj)*2 + j_][1] =                                                      \
                *(const bf16x8*)(pW + (b)*16384 + ((jj)*2 + j_) * 1024 + cs1);        \
        }                                                                             \
    } while (0)

#define MFMAQ(mh, nh)                                                                 \
    do {                                                                              \
        __builtin_amdgcn_s_setprio(1);                                                \
        _Pragma("unroll") for (int i_ = 0; i_ < 4; ++i_) {                            \
            _Pragma("unroll") for (int j_ = 0; j_ < 2; ++j_) {                        \
                acc[(mh)*4 + i_][(nh)*2 + j_] =                                       \
                    __builtin_amdgcn_mfma_f32_16x16x32_bf16(                          \
                        Af[i_][0], Wf[(nh)*2 + j_][0],                                \
                        acc[(mh)*4 + i_][(nh)*2 + j_], 0, 0, 0);                      \
                acc[(mh)*4 + i_][(nh)*2 + j_] =                                       \
                    __builtin_amdgcn_mfma_f32_16x16x32_bf16(                          \
                        Af[i_][1], Wf[(nh)*2 + j_][1],                                \
                        acc[(mh)*4 + i_][(nh)*2 + j_], 0, 0, 0);                      \
            }                                                                         \
        }                                                                             \
        __builtin_amdgcn_s_setprio(0);                                                \
    } while (0)

// Prologue: tile0 (4 half-tiles) + tile1 {W-h0, A-h0}; vmcnt(4) => tile0 landed.
#define GEMM8_LOOP(NI_, SA, SW)                                                       \
    SA(0, 0, 0);                                                                      \
    SA(0, 0, 1);                                                                      \
    SW(0, 0, 0);                                                                      \
    SW(0, 0, 1);                                                                      \
    SW(1, 1, 0);                                                                      \
    SA(1, 1, 0);                                                                      \
    VMCNT(4);                                                                         \
    PH_BAR();                                                                         \
    for (int I_ = 0; I_ < (NI_); ++I_) {                                              \
        const int t_ = 2 * I_;                                                        \
        const bool more_ = (I_ < (NI_)-1);                                            \
        /* P1 */                                                                      \
        LDA_(0, 0);                                                                   \
        LDW_(0, 0);                                                                   \
        SW(1, t_ + 1, 1);                                                             \
        PH_BAR();                                                                     \
        MFMAQ(0, 0);                                                                  \
        PH_BAR();                                                                     \
        /* P2 */                                                                      \
        LDW_(0, 1);                                                                   \
        SA(1, t_ + 1, 1);                                                             \
        PH_BAR();                                                                     \
        MFMAQ(0, 1);                                                                  \
        PH_BAR();                                                                     \
        /* P3 */                                                                      \
        LDA_(0, 1);                                                                   \
        if (more_) SW(0, t_ + 2, 0);                                                  \
        PH_BAR();                                                                     \
        MFMAQ(1, 0);                                                                  \
        PH_BAR();                                                                     \
        /* P4 */                                                                      \
        if (more_) SW(0, t_ + 2, 1);                                                  \
        PH_BAR();                                                                     \
        MFMAQ(1, 1);                                                                  \
        PH_FENCE();                                                                   \
        if (more_) { VMCNT(4); } else { VMCNT(0); }                                   \
        PH_BAR();                                                                     \
        /* P5 */                                                                      \
        LDA_(1, 0);                                                                   \
        LDW_(1, 0);                                                                   \
        if (more_) SA(0, t_ + 2, 0);                                                  \
        PH_BAR();                                                                     \
        MFMAQ(0, 0);                                                                  \
        PH_BAR();                                                                     \
        /* P6 */                                                                      \
        LDW_(1, 1);                                                                   \
        if (more_) SA(0, t_ + 2, 1);                                                  \
        PH_BAR();                                                                     \
        MFMAQ(0, 1);                                                                  \
        PH_BAR();                                                                     \
        /* P7 */                                                                      \
        LDA_(1, 1);                                                                   \
        if (more_) SW(1, t_ + 3, 0);                                                  \
        PH_BAR();                                                                     \
        MFMAQ(1, 0);                                                                  \
        PH_BAR();                                                                     \
        /* P8 */                                                                      \
        if (more_) SA(1, t_ + 3, 0);                                                  \
        PH_BAR();                                                                     \
        MFMAQ(1, 1);                                                                  \
        PH_FENCE();                                                                   \
        if (more_) {                                                                  \
            VMCNT(4);                                                                 \
            PH_BAR();                                                                 \
        }                                                                             \
    }

// ============ G1: f,o gates, plain bf16, 8-phase ============
__global__ __launch_bounds__(512, 2) void gemm8_fo(const u16* __restrict__ A,
                                                   const u16* __restrict__ W,
                                                   const float* __restrict__ bxv,
                                                   const float* __restrict__ bhv,
                                                   u16* __restrict__ out) {
    constexpr int NKT = 24, NI = NKT / 2;
    __shared__ u16 sm[65536];  // 128 KiB

    const int tid = threadIdx.x, wid = tid >> 6, lane = tid & 63;
    const int wm = wid >> 2, wn = wid & 3;
    // T1: XCD-aware swizzle; grid 512 = 8 XCD x 64, mt-major within XCD.
    const int id = blockIdx.x;
    const int wgid = (id & 7) * 64 + (id >> 3);
    const int mt = wgid >> 4, nt = wgid & 15;
    const size_t rowA0 = (size_t)mt * 256;
    const size_t rowW0 = (nt < 8) ? (2048 + (size_t)nt * 256) : (4096 + (size_t)nt * 256);

    // staging lane constants (inverse swizzle on global source)
    const int rl = lane >> 3;
    const int cl8 = ((lane & 7) ^ rl) * 8;
    // frag-read constants (swizzled chunk offsets, in u16)
    const int r15 = lane & 15, q4 = lane >> 4, x7 = lane & 7;
    const int cs0 = (q4 ^ x7) * 8;
    const int cs1 = ((q4 + 4) ^ x7) * 8;
    u16* pA = sm + ((size_t)wm * 128 + r15) * 64;
    u16* pW = sm + 32768 + ((size_t)wn * 64 + r15) * 64;

#define STG_A_FO(b, kt, hh)                                                           \
    do {                                                                              \
        const u16* s_ = A + (rowA0 + (hh)*128 + wid * 8 + rl) * (size_t)1536 +        \
                        (kt)*64 + cl8;                                                \
        u16* d_ = sm + (b)*16384 + ((hh)*128 + wid * 8) * 64;                         \
        gl_lds(s_, d_);                                                               \
        gl_lds(s_ + (size_t)64 * 1536, d_ + 4096);                                    \
    } while (0)
#define STG_W_FO(b, kt, hh)                                                           \
    do {                                                                              \
        const u16* s_ = W + (rowW0 + (hh)*128 + wid * 8 + rl) * (size_t)1536 +        \
                        (kt)*64 + cl8;                                                \
        u16* d_ = sm + 32768 + (b)*16384 + ((hh)*128 + wid * 8) * 64;                 \
        gl_lds(s_, d_);                                                               \
        gl_lds(s_ + (size_t)64 * 1536, d_ + 4096);                                    \
    } while (0)

    f32x4 acc[8][4] = {};
    bf16x8 Af[4][2], Wf[4][2];

    GEMM8_LOOP(NI, STG_A_FO, STG_W_FO);
#undef STG_A_FO
#undef STG_W_FO

    // epilogue: bias + bf16 store to Gfo[B,4096]
    const size_t mBase = (size_t)mt * 256 + wm * 128;
#pragma unroll
    for (int j = 0; j < 4; ++j) {
        const size_t n = (size_t)nt * 256 + wn * 64 + j * 16 + r15;
        const size_t g = (n < 2048) ? (2048 + n) : (4096 + n);
        const float bias = bxv[g] + bhv[g];
#pragma unroll
        for (int i = 0; i < 8; ++i) {
            const size_t m0 = mBase + i * 16 + q4 * 4;
#pragma unroll
            for (int v = 0; v < 4; ++v)
                out[(m0 + v) * 4096 + n] = f2b(acc[i][j][v] + bias);
        }
    }
}

// ============ G2: i,c as one K=4608 GEMM + fused cell, 8-phase ============
// N interleave: tile nt covers i-gates h in [nt*128,(nt+1)*128) (cols 0..127)
// and c-gates same h-range (cols 128..255), so the cell fuses per-block.
__global__ __launch_bounds__(512, 2) void gemm8_ic_cell(
    const u16* __restrict__ Ahi, const u16* __restrict__ Alo,
    const u16* __restrict__ Whi, const u16* __restrict__ Wlo,
    const float* __restrict__ bxv, const float* __restrict__ bhv,
    const u16* __restrict__ Gfo, const float* __restrict__ cx,
    float* __restrict__ ct, u16* __restrict__ U) {
    constexpr int NKT = 72, NI = NKT / 2;  // 3 x 24 K-tiles (hi*hi, lo*hi, hi*lo)
    __shared__ u16 sm[65536];  // 128 KiB; reused as float[128][256] c-buffer in epilogue

    const int tid = threadIdx.x, wid = tid >> 6, lane = tid & 63;
    const int wm = wid >> 2, wn = wid & 3;
    const int id = blockIdx.x;
    const int wgid = (id & 7) * 64 + (id >> 3);
    const int mt = wgid >> 4, nt = wgid & 15;
    const size_t rowA0 = (size_t)mt * 256;
    const size_t h0t = (size_t)nt * 128;

    const int rl = lane >> 3;
    const int cl8 = ((lane & 7) ^ rl) * 8;
    const int r15 = lane & 15, q4 = lane >> 4, x7 = lane & 7;
    const int cs0 = (q4 ^ x7) * 8;
    const int cs1 = ((q4 + 4) ^ x7) * 8;
    u16* pA = sm + ((size_t)wm * 128 + r15) * 64;
    u16* pW = sm + 32768 + ((size_t)wn * 64 + r15) * 64;

    // A' = [Ahi | Alo | Ahi]; W' rows: half0 = i (Whi@h / Wlo@h), half1 = c
    // (Whi@4096+h / Wlo@2048+h). kt<48 -> hi plane, kt>=48 -> lo plane.
#define STG_A_IC(b, kt, hh)                                                           \
    do {                                                                              \
        const int p_ = (kt) / 24;                                                     \
        const int kc_ = ((kt) % 24) * 64;                                             \
        const u16* base_ = (p_ == 1) ? Alo : Ahi;                                     \
        const u16* s_ = base_ + (rowA0 + (hh)*128 + wid * 8 + rl) * (size_t)1536 +    \
                        kc_ + cl8;                                                    \
        u16* d_ = sm + (b)*16384 + ((hh)*128 + wid * 8) * 64;                         \
        gl_lds(s_, d_);                                                               \
        gl_lds(s_ + (size_t)64 * 1536, d_ + 4096);                                    \
    } while (0)
#define STG_W_IC(b, kt, hh)                                                           \
    do {                                                                              \
        const int kc_ = ((kt) % 24) * 64;                                             \
        const u16* wp_ = ((kt) < 48) ? Whi : Wlo;                                     \
        const size_t rb_ = h0t + ((hh) ? (((kt) < 48) ? (size_t)4096 : (size_t)2048)  \
                                       : (size_t)0);                                  \
        const u16* s_ = wp_ + (rb_ + wid * 8 + rl) * (size_t)1536 + kc_ + cl8;        \
        u16* d_ = sm + 32768 + (b)*16384 + ((hh)*128 + wid * 8) * 64;                 \
        gl_lds(s_, d_);                                                               \
        gl_lds(s_ + (size_t)64 * 1536, d_ + 4096);                                    \
    } while (0)

    f32x4 acc[8][4] = {};
    bf16x8 Af[4][2], Wf[4][2];

    GEMM8_LOOP(NI, STG_A_IC, STG_W_IC);
#undef STG_A_IC
#undef STG_W_IC

    // ---- fused LSTM cell epilogue ----
    // c-waves (wn>=2) publish c (+bias) via LDS; i-waves (wn<2) fuse the cell.
    __syncthreads();  // all waves done with K-loop LDS before reuse
    float* cb = (float*)sm;  // [128 h][256 m]
    const size_t mBase = (size_t)mt * 256 + wm * 128;
    if (wn >= 2) {
#pragma unroll
        for (int j = 0; j < 4; ++j) {
            const int hl = (wn - 2) * 64 + j * 16 + r15;
            const size_t h = h0t + hl;
            const float bc = bxv[4096 + h] + bhv[4096 + h];
#pragma unroll
            for (int i = 0; i < 8; ++i) {
                f32x4 v = acc[i][j];
                v[0] += bc; v[1] += bc; v[2] += bc; v[3] += bc;
                *(f32x4*)&cb[(size_t)hl * 256 + wm * 128 + i * 16 + q4 * 4] = v;
            }
        }
    }
    __syncthreads();
    if (wn < 2) {
#pragma unroll
        for (int j = 0; j < 4; ++j) {
            const int hl = wn * 64 + j * 16 + r15;
            const size_t h = h0t + hl;
            const float bi = bxv[h] + bhv[h];
#pragma unroll
            for (int i = 0; i < 8; ++i) {
                const size_t m0 = mBase + i * 16 + q4 * 4;
                const f32x4 cv =
                    *(const f32x4*)&cb[(size_t)hl * 256 + wm * 128 + i * 16 + q4 * 4];
#pragma unroll
                for (int v = 0; v < 4; ++v) {
                    const size_t m = m0 + v;
                    const float iv = acc[i][j][v] + bi;
                    const float f = b2f(Gfo[m * 4096 + h]);
                    const float o = b2f(Gfo[m * 4096 + 2048 + h]);
                    const float c_ = f * cx[m * 2048 + h] + iv * cv[v];
                    ct[m * 2048 + h] = c_;
                    U[m * 2048 + h] = f2b(o * fast_tanh(c_));
                }
            }
        }
    }
}

// ============ proj: ht[B,512] = U[B,2048] * Wp[512,2048]^T, dbuf (unchanged) ============
__global__ __launch_bounds__(256, 2) void gemm_proj(const u16* __restrict__ A,
                                                    const u16* __restrict__ W,
                                                    float* __restrict__ out) {
    constexpr int K = 2048, BK = 32;
    constexpr int AB = 128 * BK;
    constexpr int WB = 64 * BK;
    __shared__ u16 As[2 * AB];
    __shared__ u16 Ws[2 * WB];

    const int tid = threadIdx.x, wave = tid >> 6, lane = tid & 63;
    const size_t tileM = (size_t)blockIdx.y * 128;
    const size_t tileN = (size_t)blockIdx.x * 64;
    const int waveM = (wave >> 1) * 64;
    const int waveN = (wave & 1) * 32;

    const int srow = lane >> 2, scol = (lane & 3) * 8;
    const u16* Ag = A + (tileM + (size_t)(wave * 16 + srow)) * K + scol;
    const u16* Wg = W + (tileN + (size_t)(wave * 16 + srow)) * K + scol;
    const int lA0 = (wave * 16) * BK;
    const int lA1 = (wave * 16 + 64) * BK;

    f32x4 acc[4][2] = {};
    const int arow = waveM + (lane & 15);
    const int wrow = waveN + (lane & 15);
    const int kq = (lane >> 4) * 8;

#define STAGE_PR(b, k0)                                        \
    do {                                                       \
        gl_lds(Ag + (k0), &As[(b)*AB + lA0]);                  \
        gl_lds(Ag + (size_t)64 * K + (k0), &As[(b)*AB + lA1]); \
        gl_lds(Wg + (k0), &Ws[(b)*WB + lA0]);                  \
    } while (0)

#define COMPUTE_PR(b)                                                          \
    do {                                                                       \
        bf16x8 af[4], wf[2];                                                   \
        _Pragma("unroll") for (int i = 0; i < 4; ++i)                          \
            af[i] = *(const bf16x8*)&As[(b)*AB + (arow + i * 16) * BK + kq];   \
        _Pragma("unroll") for (int j = 0; j < 2; ++j)                          \
            wf[j] = *(const bf16x8*)&Ws[(b)*WB + (wrow + j * 16) * BK + kq];   \
        _Pragma("unroll") for (int i = 0; i < 4; ++i)                          \
            _Pragma("unroll") for (int j = 0; j < 2; ++j)                      \
                acc[i][j] = __builtin_amdgcn_mfma_f32_16x16x32_bf16(           \
                    af[i], wf[j], acc[i][j], 0, 0, 0);                         \
    } while (0)

    STAGE_PR(0, 0);
    __syncthreads();
    for (int k0 = 0; k0 < K; k0 += 2 * BK) {
        STAGE_PR(1, k0 + BK);
        COMPUTE_PR(0);
        __syncthreads();
        if (k0 + 2 * BK < K) STAGE_PR(0, k0 + 2 * BK);
        COMPUTE_PR(1);
        __syncthreads();
    }
#undef STAGE_PR
#undef COMPUTE_PR

    const int rq = (lane >> 4) * 4;
#pragma unroll
    for (int i = 0; i < 4; ++i) {
        const size_t rbase = tileM + waveM + i * 16 + rq;
#pragma unroll
        for (int j = 0; j < 2; ++j) {
            const size_t n = tileN + waveN + (lane & 15) + j * 16;
#pragma unroll
            for (int v = 0; v < 4; ++v)
                out[(rbase + v) * 512 + n] = acc[i][j][v];
        }
    }
}

// ============ launch ============
extern "C" void kernel_launch(void* const* d_in, const int* in_sizes, int n_in,
                              void* d_out, int out_size, void* d_ws, size_t ws_size,
                              hipStream_t stream) {
    const float* input  = (const float*)d_in[0];
    const float* hx     = (const float*)d_in[1];
    const float* cx     = (const float*)d_in[2];
    const float* w_x    = (const float*)d_in[3];
    const float* b_x    = (const float*)d_in[4];
    const float* w_h    = (const float*)d_in[5];
    const float* b_h    = (const float*)d_in[6];
    const float* w_proj = (const float*)d_in[7];

    constexpr int H = 2048, P = 512, B = 8192;

    char* ws = (char*)d_ws;
    u16* Ahi = (u16*)(ws);                 // [8192,1536] 25,165,824
    u16* Alo = (u16*)(ws + 25165824);      // [8192,1536] 25,165,824
    u16* Whi = (u16*)(ws + 50331648);      // [8192,1536] 25,165,824
    u16* Wlo = (u16*)(ws + 75497472);      // [4096,1536] 12,582,912
    u16* Gfo = (u16*)(ws + 88080384);      // [8192,4096] 67,108,864
    u16* U   = (u16*)(ws + 155189248);     // [8192,2048] 33,554,432
    u16* Wp  = (u16*)(ws + 188743680);     // [512,2048]   2,097,152

    float* ht = (float*)d_out;
    float* ct = (float*)d_out + (size_t)B * P;

    pack_A<<<B, 384, 0, stream>>>(input, hx, Ahi, Alo);
    pack_W<<<4 * H, 384, 0, stream>>>(w_x, w_h, Whi, Wlo);
    pack_flat_bf16<<<(P * H / 4) / 256, 256, 0, stream>>>(w_proj, Wp);

    gemm8_fo<<<512, 512, 0, stream>>>(Ahi, Whi, b_x, b_h, Gfo);
    gemm8_ic_cell<<<512, 512, 0, stream>>>(Ahi, Alo, Whi, Wlo, b_x, b_h,
                                           Gfo, cx, ct, U);
    gemm_proj<<<dim3(8, 64), 256, 0, stream>>>(U, Wp, ht);
}